// Round 7
// baseline (217.807 us; speedup 1.0000x reference)
//
#include <hip/hip_runtime.h>

#define N_NODES 57254
#define N_EDGES 916064
#define DIM 128
#define NHEAD 8
#define BT (64*512)
#define NBKT 224                 // dst>>8 buckets (57254>>8 == 223)
#define NCHUNK 256
#define CHUNK 3579               // ceil(916064/256)

typedef __attribute__((ext_vector_type(8))) short short8v;
typedef __attribute__((ext_vector_type(4))) float f32x4;

static __device__ __forceinline__ unsigned short f2bf(float f){
  unsigned int b = __builtin_bit_cast(unsigned int, f);
  b += 0x7fffu + ((b >> 16) & 1u);           // round-to-nearest-even
  return (unsigned short)(b >> 16);
}
static __device__ __forceinline__ float lo16f(unsigned int zz){
  return __builtin_bit_cast(float, zz << 16);
}
static __device__ __forceinline__ float hi16f(unsigned int zz){
  return __builtin_bit_cast(float, zz & 0xffff0000u);
}

// ---------------- CSR build: two-level counting sort, no global atomics ----------------

__global__ __launch_bounds__(256) void p1hist(const int* __restrict__ dst,
                                              int* __restrict__ bh){
  __shared__ int h[NBKT];
  int t = threadIdx.x, c = blockIdx.x;
  if (t < NBKT) h[t] = 0;
  __syncthreads();
  int lo = c*CHUNK, hi = lo + CHUNK; if (hi > N_EDGES) hi = N_EDGES;
  for (int i = lo + t; i < hi; i += 256)
    atomicAdd(&h[((unsigned)dst[i]) >> 8], 1);
  __syncthreads();
  if (t < NBKT) bh[t*NCHUNK + c] = h[t];     // bucket-major layout for scan
}

__global__ void scan_partial(const int* __restrict__ in, int* __restrict__ out,
                             int* __restrict__ bsum, int n){
  __shared__ int sm[256];
  int tid = threadIdx.x;
  int i = blockIdx.x*256 + tid;
  int v = (i < n) ? in[i] : 0;
  sm[tid] = v;
  __syncthreads();
  #pragma unroll
  for (int d = 1; d < 256; d <<= 1){
    int add = (tid >= d) ? sm[tid - d] : 0;
    __syncthreads();
    sm[tid] += add;
    __syncthreads();
  }
  if (i < n) out[i] = sm[tid] - v;
  if (tid == 255) bsum[blockIdx.x] = sm[255];
}

// block b adds sum(bsum[0..b)) to its 256 elements
__global__ void scan_add2(int* __restrict__ out, const int* __restrict__ bsum,
                          int nb, int n){
  __shared__ int sm[256];
  int t = threadIdx.x, b = blockIdx.x;
  sm[t] = (t < b && t < nb) ? bsum[t] : 0;
  __syncthreads();
  #pragma unroll
  for (int d = 128; d; d >>= 1){
    if (t < d) sm[t] += sm[t + d];
    __syncthreads();
  }
  int i = b*256 + t;
  if (i < n) out[i] += sm[0];
}

// Phase 1b: LDS-staged coarse scatter. Edge packed as (src<<16)|(dst&255).
__global__ __launch_bounds__(256) void p1scat(const int* __restrict__ src,
                                              const int* __restrict__ dst,
                                              const int* __restrict__ bases,
                                              unsigned* __restrict__ ebuf){
  __shared__ unsigned stage[CHUNK];
  __shared__ short bkt_of[CHUNK];
  __shared__ int lh[256], smm[256], ls[NBKT+1], cur[NBKT], gb[NBKT];
  int t = threadIdx.x, c = blockIdx.x;
  lh[t] = 0;
  __syncthreads();
  int lo = c*CHUNK, hi = lo + CHUNK; if (hi > N_EDGES) hi = N_EDGES;
  int len = hi - lo;
  for (int i = lo + t; i < hi; i += 256)
    atomicAdd(&lh[((unsigned)dst[i]) >> 8], 1);
  __syncthreads();
  int v = lh[t];
  smm[t] = v;
  __syncthreads();
  #pragma unroll
  for (int d = 1; d < 256; d <<= 1){
    int add = (t >= d) ? smm[t - d] : 0;
    __syncthreads();
    smm[t] += add;
    __syncthreads();
  }
  if (t < NBKT){ ls[t] = smm[t] - v; cur[t] = smm[t] - v; gb[t] = bases[t*NCHUNK + c]; }
  if (t == 255) ls[NBKT] = smm[255];          // == len
  __syncthreads();
  if (t < NBKT){
    int e0 = ls[t], e1 = ls[t+1];
    for (int k = e0; k < e1; ++k) bkt_of[k] = (short)t;
  }
  __syncthreads();
  for (int i = lo + t; i < hi; i += 256){
    unsigned d = (unsigned)dst[i];
    int b = d >> 8;
    int pos = atomicAdd(&cur[b], 1);
    stage[pos] = (((unsigned)src[i]) << 16) | (d & 255u);
  }
  __syncthreads();
  for (int k = t; k < len; k += 256){
    int b = bkt_of[k];
    ebuf[gb[b] + (k - ls[b])] = stage[k];
  }
}

// Phase 2: per-bucket fine sort -> offs + csr
__global__ __launch_bounds__(256) void p2fine(const unsigned* __restrict__ ebuf,
                                              const int* __restrict__ bases,
                                              int* __restrict__ offs,
                                              int* __restrict__ csr){
  __shared__ int cnt[256], sm[256], loff[256], cur[256];
  int t = threadIdx.x, b = blockIdx.x;
  int bstart = bases[b*NCHUNK];
  int bend   = (b < NBKT-1) ? bases[(b+1)*NCHUNK] : N_EDGES;
  cnt[t] = 0;
  __syncthreads();
  for (int i = bstart + t; i < bend; i += 256)
    atomicAdd(&cnt[ebuf[i] & 255u], 1);
  __syncthreads();
  int v = cnt[t];
  sm[t] = v;
  __syncthreads();
  #pragma unroll
  for (int d = 1; d < 256; d <<= 1){
    int add = (t >= d) ? sm[t - d] : 0;
    __syncthreads();
    sm[t] += add;
    __syncthreads();
  }
  loff[t] = sm[t] - v;
  cur[t]  = bstart + sm[t] - v;
  int nlo = b*256;
  int nn  = N_NODES - nlo; if (nn > 256) nn = 256;
  if (t < nn) offs[nlo + t] = bstart + loff[t];
  if (b == NBKT-1 && t == 0) offs[N_NODES] = N_EDGES;
  __syncthreads();
  for (int i = bstart + t; i < bend; i += 256){
    unsigned e = ebuf[i];
    int pos = atomicAdd(&cur[e & 255u], 1);
    csr[pos] = (int)(e >> 16);
  }
}

// ---------------- W transpose -> bf16 Wt[c][k], both layers in one launch ----------------
__global__ void twt_kernel(const float* __restrict__ W0, const float* __restrict__ W1,
                           unsigned short* __restrict__ Wt0, unsigned short* __restrict__ Wt1){
  int t = blockIdx.x*256 + threadIdx.x;   // 0..32767
  int which = t >> 14;
  int i = t & 16383;
  int c = i >> 7, k = i & 127;
  const float* W = which ? W1 : W0;
  unsigned short* Wt = which ? Wt1 : Wt0;
  Wt[i] = f2bf(W[k*128 + c]);
}

// ---------------- GEMM: Z(bf16) = A @ W, fused el/er epilogue ----------------
// B fragments loaded direct from global Wt (L2-hot, fragment-contiguous layout).
// MODE 0: A f32 + row-gather via LDS (also emits Hb bf16 copy). MODE 1: A bf16,
// fragments loaded direct from global — no staging, no main-loop syncs.
// Epilogue: acc -> LDS (bf16, swizzled) -> row-linear 16B stores (full-line writes).
template<int MODE>
__global__ __launch_bounds__(256) void gemm_nt(
    const void* __restrict__ Av, const int* __restrict__ gidx,
    const unsigned short* __restrict__ Wt,   // bf16 [col][k]
    const float* __restrict__ al, const float* __restrict__ ar,
    unsigned short* __restrict__ Z,          // bf16 [N][128]
    float* __restrict__ elp, float* __restrict__ erp,
    unsigned short* __restrict__ Hb)
{
  __shared__ unsigned short As[64*128];      // 16KB (A tile in MODE 0; Z transpose buffer)
  int t = threadIdx.x;
  int brow = blockIdx.x * 64;
  int w = t >> 6, lane = t & 63;
  int o = lane & 15;

  if (MODE == 0){
    int r = t >> 2, q = t & 3;               // 4 threads per row, 32 cols each
    int grow = brow + r;
    bool valid = grow < N_NODES;
    const float* A = (const float*)Av;
    unsigned srcr = valid ? (unsigned)gidx[grow] : 0u;
    const float* arow = A + (size_t)srcr * DIM;
    #pragma unroll
    for (int j = 0; j < 4; ++j){
      int c = q*32 + j*8;
      float4 a0, a1;
      if (valid){ a0 = *(const float4*)(arow + c); a1 = *(const float4*)(arow + c + 4); }
      else { a0 = make_float4(0.f,0.f,0.f,0.f); a1 = a0; }
      short8v pk;
      pk[0]=(short)f2bf(a0.x); pk[1]=(short)f2bf(a0.y); pk[2]=(short)f2bf(a0.z); pk[3]=(short)f2bf(a0.w);
      pk[4]=(short)f2bf(a1.x); pk[5]=(short)f2bf(a1.y); pk[6]=(short)f2bf(a1.z); pk[7]=(short)f2bf(a1.w);
      if (valid) *(short8v*)(Hb + (unsigned)grow*128u + c) = pk;
      int byte = (r*256 + c*2) ^ ((r & 7) << 4);
      *(short8v*)((char*)As + byte) = pk;
    }
    __syncthreads();
  }

  f32x4 acc[8];
  #pragma unroll
  for (int n=0;n<8;n++) acc[n] = (f32x4){0.f,0.f,0.f,0.f};
  int arow_l = w*16 + o;                      // local A row for this lane
  const unsigned short* Abf = (const unsigned short*)Av;
  int arow_g = brow + arow_l;
  if (MODE == 1 && arow_g >= N_NODES) arow_g = 0;   // clamp (stores guarded)
  #pragma unroll
  for (int kk = 0; kk < 4; ++kk){
    int ks = kk*32 + (lane>>4)*8;
    short8v a;
    if (MODE == 0){
      int abyte = (arow_l*256 + ks*2) ^ ((arow_l & 7) << 4);
      a = *(const short8v*)((const char*)As + abyte);
    } else {
      a = *(const short8v*)(Abf + (unsigned)arow_g*128u + ks);
    }
    short8v b[8];
    #pragma unroll
    for (int n=0;n<8;n++)
      b[n] = *(const short8v*)(Wt + (unsigned)(n*16 + o)*128u + ks);
    #pragma unroll
    for (int n=0;n<8;n++)
      acc[n] = __builtin_amdgcn_mfma_f32_16x16x32_bf16(a, b[n], acc[n], 0, 0, 0);
  }

  // ---- Z epilogue via LDS transpose ----
  __syncthreads();                            // MODE 0: A reads done; MODE 1: first sync
  int row0 = w*16 + ((lane>>4)<<2);           // local row base for acc rows
  #pragma unroll
  for (int n=0;n<8;n++){
    #pragma unroll
    for (int r=0;r<4;r++){
      int rl = row0 + r;
      int byte = (rl*256 + (n*16 + o)*2) ^ ((rl & 7) << 4);
      *(unsigned short*)((char*)As + byte) = f2bf(acc[n][r]);
    }
  }
  __syncthreads();
  {
    int rl = t >> 2, q = t & 3;
    int grow = brow + rl;
    if (grow < N_NODES){
      #pragma unroll
      for (int c2=0;c2<4;c2++){
        int byte = (rl*256 + q*64 + c2*16) ^ ((rl & 7) << 4);
        short8v v = *(const short8v*)((const char*)As + byte);
        *(short8v*)(Z + (unsigned)grow*128u + q*32 + c2*8) = v;
      }
    }
  }

  // ---- fused el/er ----
  #pragma unroll
  for (int n=0;n<8;n++){
    float a_l = al[n*16 + o];
    float a_r = ar[n*16 + o];
    #pragma unroll
    for (int r=0;r<4;r++){
      float sl = acc[n][r] * a_l;
      float sr = acc[n][r] * a_r;
      #pragma unroll
      for (int m=1;m<16;m<<=1){
        sl += __shfl_xor(sl, m, 64);
        sr += __shfl_xor(sr, m, 64);
      }
      int grow = brow + row0 + r;
      if (o == n && grow < N_NODES){
        elp[(unsigned)grow*8u + n] = sl;
        erp[(unsigned)grow*8u + n] = sr;
      }
    }
  }
}

// ---------------- per-node attention aggregate + residual + bias (+act) ----------------
__global__ __launch_bounds__(256) void edge_agg(
    const unsigned short* __restrict__ Z, const float* __restrict__ el,
    const float* __restrict__ er, const int* __restrict__ off,
    const int* __restrict__ csr, const unsigned short* __restrict__ Hin,
    const float* __restrict__ bias, unsigned short* __restrict__ Hout,
    int activate)
{
  int tid  = threadIdx.x;
  int lane = tid & 63;
  int n    = __builtin_amdgcn_readfirstlane((int)(blockIdx.x*4 + (tid >> 6)));
  if (n >= N_NODES) return;
  int head = lane >> 3;

  int lo = off[n], hi = off[n+1];
  float ern = er[(unsigned)n*8u + head];
  float acc0a=0.f, acc0b=0.f, acc1a=0.f, acc1b=0.f, sacca=0.f, saccb=0.f;
  const unsigned lidx = (unsigned)(lane*2);          // ushort index within row

  for (int base = lo; base < hi; base += 16){
    int s[16]; float x[16]; unsigned zz[16]; float wv[16];
    #pragma unroll
    for (int j=0;j<16;++j){
      int idx = base + j;
      s[j] = csr[idx < hi ? idx : hi-1];
    }
    #pragma unroll
    for (int j=0;j<16;++j) x[j] = el[(unsigned)s[j]*8u + head] + ern;
    #pragma unroll
    for (int j=0;j<16;++j) zz[j] = *(const unsigned*)(Z + (unsigned)s[j]*128u + lidx);
    #pragma unroll
    for (int j=0;j<16;++j){
      float xv = fmaxf(x[j], 0.2f*x[j]);             // leaky_relu 0.2
      wv[j] = (base + j < hi) ? __expf(xv) : 0.f;    // masked (no max-shift: |e|<<1)
    }
    #pragma unroll
    for (int j=0;j<16;j+=2){
      sacca += wv[j];           saccb += wv[j+1];
      acc0a += wv[j]*lo16f(zz[j]);   acc0b += wv[j+1]*lo16f(zz[j+1]);
      acc1a += wv[j]*hi16f(zz[j]);   acc1b += wv[j+1]*hi16f(zz[j+1]);
    }
  }
  float sacc = sacca + saccb;
  float acc0 = acc0a + acc0b;
  float acc1 = acc1a + acc1b;
  float inv = (hi > lo) ? (1.f / sacc) : 0.f;
  unsigned hv = *(const unsigned*)(Hin + (unsigned)n*128u + lidx);
  int d = lane*2;
  float r0 = acc0*inv + lo16f(hv) + bias[d];
  float r1 = acc1*inv + hi16f(hv) + bias[d+1];
  if (activate){
    r0 = (r0 > 0.f) ? r0 : 0.01f*r0;
    r1 = (r1 > 0.f) ? r1 : 0.01f*r1;
  }
  unsigned outv = ((unsigned)f2bf(r1) << 16) | (unsigned)f2bf(r0);
  *(unsigned*)(Hout + (unsigned)n*128u + lidx) = outv;
}

// ---------------- L2 normalize + gather out = v[x] ----------------
__global__ __launch_bounds__(256) void norm_gather(const unsigned short* __restrict__ H,
    const int* __restrict__ x, float* __restrict__ out)
{
  int row = blockIdx.x*4 + (threadIdx.x >> 6);
  if (row >= BT) return;
  int lane = threadIdx.x & 63;
  unsigned xi = (unsigned)x[row];
  unsigned hv = *(const unsigned*)(H + xi*128u + (unsigned)(lane*2));
  float v0 = lo16f(hv), v1 = hi16f(hv);
  float ss = v0*v0 + v1*v1;
  #pragma unroll
  for (int m = 32; m; m >>= 1) ss += __shfl_xor(ss, m, 64);
  float sc = 1.f / fmaxf(sqrtf(ss), 1e-5f);
  int d = lane*2;
  out[(size_t)row*128 + d]     = v0*sc;
  out[(size_t)row*128 + d + 1] = v1*sc;
}

extern "C" void kernel_launch(void* const* d_in, const int* in_sizes, int n_in,
                              void* d_out, int out_size, void* d_ws, size_t ws_size,
                              hipStream_t stream)
{
  const float* emb = (const float*)d_in[0];
  const float* W0  = (const float*)d_in[1];
  const float* al0 = (const float*)d_in[2];
  const float* ar0 = (const float*)d_in[3];
  const float* b0  = (const float*)d_in[4];
  const float* W1  = (const float*)d_in[5];
  const float* al1 = (const float*)d_in[6];
  const float* ar1 = (const float*)d_in[7];
  const float* b1  = (const float*)d_in[8];
  const int* n_feat = (const int*)d_in[9];
  const int* srcv = (const int*)d_in[10];
  const int* dstv = (const int*)d_in[11];
  const int* xv   = (const int*)d_in[12];
  float* out = (float*)d_out;

  char* p = (char*)d_ws;
  auto alloc = [&](size_t b)->char*{ char* q = p; p += (b + 255) & ~(size_t)255; return q; };
  unsigned short* Z   = (unsigned short*)alloc((size_t)N_NODES*128*2);
  unsigned short* H1b = (unsigned short*)alloc((size_t)N_NODES*128*2);  // layer0 out, layer1 in/out
  unsigned short* Hb0 = (unsigned short*)alloc((size_t)N_NODES*128*2);  // bf16 gathered emb rows
  int* offs  = (int*)alloc((size_t)(N_NODES+1)*4);
  int* csr   = (int*)alloc((size_t)N_EDGES*4);
  unsigned* ebuf = (unsigned*)alloc((size_t)N_EDGES*4);  // dead after p2fine; reused for el/er
  int* bh    = (int*)alloc((size_t)NBKT*NCHUNK*4);
  int* bsum  = (int*)alloc(256*4);
  unsigned short* Wt0 = (unsigned short*)alloc(128*128*2);
  unsigned short* Wt1 = (unsigned short*)alloc(128*128*2);
  float* el = (float*)ebuf;                              // N*8 floats
  float* er = el + (size_t)N_NODES*8;                    // N*8 floats (2*N*8*4 == E*4)

  const int NSCAN = NBKT*NCHUNK;                         // 57344

  // CSR build (no global atomics)
  p1hist<<<NCHUNK, 256, 0, stream>>>(dstv, bh);
  scan_partial<<<NSCAN/256, 256, 0, stream>>>(bh, bh, bsum, NSCAN);
  scan_add2<<<NSCAN/256, 256, 0, stream>>>(bh, bsum, NSCAN/256, NSCAN);
  p1scat<<<NCHUNK, 256, 0, stream>>>(srcv, dstv, bh, ebuf);
  p2fine<<<NBKT, 256, 0, stream>>>(ebuf, bh, offs, csr);

  twt_kernel<<<128, 256, 0, stream>>>(W0, W1, Wt0, Wt1);

  int gemm_grid = (N_NODES + 63)/64;
  int agg_grid  = (N_NODES + 3)/4;

  // layer 0 (rows gathered emb[n_feat] -> also Hb0; activation on)
  gemm_nt<0><<<gemm_grid, 256, 0, stream>>>(emb, n_feat, Wt0, al0, ar0, Z, el, er, Hb0);
  edge_agg<<<agg_grid, 256, 0, stream>>>(Z, el, er, offs, csr, Hb0, b0, H1b, 1);
  // layer 1 (bf16 input; in-place residual safe: wave reads row n before writing it)
  gemm_nt<1><<<gemm_grid, 256, 0, stream>>>(H1b, nullptr, Wt1, al1, ar1, Z, el, er, nullptr);
  edge_agg<<<agg_grid, 256, 0, stream>>>(Z, el, er, offs, csr, H1b, b1, H1b, 0);
  // normalize + output gather
  norm_gather<<<(BT + 3)/4, 256, 0, stream>>>(H1b, xv, out);
}

// Round 8
// 182.992 us; speedup vs baseline: 1.1903x; 1.1903x over previous
//
#include <hip/hip_runtime.h>

#define N_NODES 57254
#define N_EDGES 916064
#define DIM 128
#define NHEAD 8
#define BT (64*512)
#define NBKT 224                 // dst>>8 buckets (57254>>8 == 223)
#define NCHUNK 256
#define CHUNK 3579               // ceil(916064/256)

typedef __attribute__((ext_vector_type(8))) short short8v;
typedef __attribute__((ext_vector_type(4))) float f32x4;

static __device__ __forceinline__ unsigned short f2bf(float f){
  unsigned int b = __builtin_bit_cast(unsigned int, f);
  b += 0x7fffu + ((b >> 16) & 1u);           // round-to-nearest-even
  return (unsigned short)(b >> 16);
}
static __device__ __forceinline__ float bf2f(unsigned short u){
  unsigned int b = ((unsigned int)u) << 16;
  return __builtin_bit_cast(float, b);
}
static __device__ __forceinline__ float lo16f(unsigned int zz){
  return __builtin_bit_cast(float, zz << 16);
}
static __device__ __forceinline__ float hi16f(unsigned int zz){
  return __builtin_bit_cast(float, zz & 0xffff0000u);
}

// ---------------- CSR build: two-level counting sort, no global atomics ----------------

__global__ __launch_bounds__(256) void p1hist(const int* __restrict__ dst,
                                              int* __restrict__ bh){
  __shared__ int h[NBKT];
  int t = threadIdx.x, c = blockIdx.x;
  if (t < NBKT) h[t] = 0;
  __syncthreads();
  int lo = c*CHUNK, hi = lo + CHUNK; if (hi > N_EDGES) hi = N_EDGES;
  for (int i = lo + t; i < hi; i += 256)
    atomicAdd(&h[((unsigned)dst[i]) >> 8], 1);
  __syncthreads();
  if (t < NBKT) bh[t*NCHUNK + c] = h[t];     // bucket-major layout for scan
}

__global__ void scan_partial(const int* __restrict__ in, int* __restrict__ out,
                             int* __restrict__ bsum, int n){
  __shared__ int sm[256];
  int tid = threadIdx.x;
  int i = blockIdx.x*256 + tid;
  int v = (i < n) ? in[i] : 0;
  sm[tid] = v;
  __syncthreads();
  #pragma unroll
  for (int d = 1; d < 256; d <<= 1){
    int add = (tid >= d) ? sm[tid - d] : 0;
    __syncthreads();
    sm[tid] += add;
    __syncthreads();
  }
  if (i < n) out[i] = sm[tid] - v;
  if (tid == 255) bsum[blockIdx.x] = sm[255];
}

// block b adds sum(bsum[0..b)) to its 256 elements
__global__ void scan_add2(int* __restrict__ out, const int* __restrict__ bsum,
                          int nb, int n){
  __shared__ int sm[256];
  int t = threadIdx.x, b = blockIdx.x;
  sm[t] = (t < b && t < nb) ? bsum[t] : 0;
  __syncthreads();
  #pragma unroll
  for (int d = 128; d; d >>= 1){
    if (t < d) sm[t] += sm[t + d];
    __syncthreads();
  }
  int i = b*256 + t;
  if (i < n) out[i] += sm[0];
}

// Phase 1b: LDS-staged coarse scatter. Edge packed as (src<<16)|(dst&255).
__global__ __launch_bounds__(256) void p1scat(const int* __restrict__ src,
                                              const int* __restrict__ dst,
                                              const int* __restrict__ bases,
                                              unsigned* __restrict__ ebuf){
  __shared__ unsigned stage[CHUNK];
  __shared__ short bkt_of[CHUNK];
  __shared__ int lh[256], smm[256], ls[NBKT+1], cur[NBKT], gb[NBKT];
  int t = threadIdx.x, c = blockIdx.x;
  lh[t] = 0;
  __syncthreads();
  int lo = c*CHUNK, hi = lo + CHUNK; if (hi > N_EDGES) hi = N_EDGES;
  int len = hi - lo;
  for (int i = lo + t; i < hi; i += 256)
    atomicAdd(&lh[((unsigned)dst[i]) >> 8], 1);
  __syncthreads();
  int v = lh[t];
  smm[t] = v;
  __syncthreads();
  #pragma unroll
  for (int d = 1; d < 256; d <<= 1){
    int add = (t >= d) ? smm[t - d] : 0;
    __syncthreads();
    smm[t] += add;
    __syncthreads();
  }
  if (t < NBKT){ ls[t] = smm[t] - v; cur[t] = smm[t] - v; gb[t] = bases[t*NCHUNK + c]; }
  if (t == 255) ls[NBKT] = smm[255];          // == len
  __syncthreads();
  if (t < NBKT){
    int e0 = ls[t], e1 = ls[t+1];
    for (int k = e0; k < e1; ++k) bkt_of[k] = (short)t;
  }
  __syncthreads();
  for (int i = lo + t; i < hi; i += 256){
    unsigned d = (unsigned)dst[i];
    int b = d >> 8;
    int pos = atomicAdd(&cur[b], 1);
    stage[pos] = (((unsigned)src[i]) << 16) | (d & 255u);
  }
  __syncthreads();
  for (int k = t; k < len; k += 256){
    int b = bkt_of[k];
    ebuf[gb[b] + (k - ls[b])] = stage[k];
  }
}

// Phase 2: per-bucket fine sort -> offs + csr
__global__ __launch_bounds__(256) void p2fine(const unsigned* __restrict__ ebuf,
                                              const int* __restrict__ bases,
                                              int* __restrict__ offs,
                                              int* __restrict__ csr){
  __shared__ int cnt[256], sm[256], loff[256], cur[256];
  int t = threadIdx.x, b = blockIdx.x;
  int bstart = bases[b*NCHUNK];
  int bend   = (b < NBKT-1) ? bases[(b+1)*NCHUNK] : N_EDGES;
  cnt[t] = 0;
  __syncthreads();
  for (int i = bstart + t; i < bend; i += 256)
    atomicAdd(&cnt[ebuf[i] & 255u], 1);
  __syncthreads();
  int v = cnt[t];
  sm[t] = v;
  __syncthreads();
  #pragma unroll
  for (int d = 1; d < 256; d <<= 1){
    int add = (t >= d) ? sm[t - d] : 0;
    __syncthreads();
    sm[t] += add;
    __syncthreads();
  }
  loff[t] = sm[t] - v;
  cur[t]  = bstart + sm[t] - v;
  int nlo = b*256;
  int nn  = N_NODES - nlo; if (nn > 256) nn = 256;
  if (t < nn) offs[nlo + t] = bstart + loff[t];
  if (b == NBKT-1 && t == 0) offs[N_NODES] = N_EDGES;
  __syncthreads();
  for (int i = bstart + t; i < bend; i += 256){
    unsigned e = ebuf[i];
    int pos = atomicAdd(&cur[e & 255u], 1);
    csr[pos] = (int)(e >> 16);
  }
}

// ---------------- W transpose -> bf16 Wt[c][k], both layers in one launch ----------------
__global__ void twt_kernel(const float* __restrict__ W0, const float* __restrict__ W1,
                           unsigned short* __restrict__ Wt0, unsigned short* __restrict__ Wt1){
  int t = blockIdx.x*256 + threadIdx.x;   // 0..32767
  int which = t >> 14;
  int i = t & 16383;
  int c = i >> 7, k = i & 127;
  const float* W = which ? W1 : W0;
  unsigned short* Wt = which ? Wt1 : Wt0;
  Wt[i] = f2bf(W[k*128 + c]);
}

// ---------------- GEMM: Z(bf16) = A @ W (round-2 shape: 128x128 tile, A+B in LDS) ----
// MODE 0: A f32 + row-gather (also emits Hb bf16 copy). MODE 1: A bf16 contiguous.
template<int MODE>
__global__ __launch_bounds__(256) void gemm_nt(
    const void* __restrict__ Av, const int* __restrict__ gidx,
    const unsigned short* __restrict__ Wt,   // bf16 [col][k]
    unsigned short* __restrict__ Z,          // bf16 [N][128]
    unsigned short* __restrict__ Hb)
{
  __shared__ unsigned short As[128*128];     // 32KB
  __shared__ unsigned short Bs[128*128];     // 32KB
  int t = threadIdx.x;
  int brow = blockIdx.x * 128;
  {
    int r = t >> 1, half = t & 1;
    int grow = brow + r;
    bool valid = grow < N_NODES;
    unsigned srcr = 0u;
    if (MODE == 0) srcr = valid ? (unsigned)gidx[grow] : 0u;
    #pragma unroll
    for (int j = 0; j < 8; ++j){
      int c = half*64 + j*8;
      short8v pk;
      if (MODE == 0){
        const float* arow = (const float*)Av + (size_t)srcr * DIM;
        float4 a0, a1;
        if (valid){ a0 = *(const float4*)(arow + c); a1 = *(const float4*)(arow + c + 4); }
        else { a0 = make_float4(0.f,0.f,0.f,0.f); a1 = a0; }
        pk[0]=(short)f2bf(a0.x); pk[1]=(short)f2bf(a0.y); pk[2]=(short)f2bf(a0.z); pk[3]=(short)f2bf(a0.w);
        pk[4]=(short)f2bf(a1.x); pk[5]=(short)f2bf(a1.y); pk[6]=(short)f2bf(a1.z); pk[7]=(short)f2bf(a1.w);
        if (valid) *(short8v*)(Hb + (unsigned)grow*128u + c) = pk;
      } else {
        const unsigned short* A = (const unsigned short*)Av;
        if (valid) pk = *(const short8v*)(A + (unsigned)grow*128u + c);
        else       pk = (short8v){0,0,0,0,0,0,0,0};
      }
      int byte = (r*256 + c*2) ^ ((r & 7) << 4);
      *(short8v*)((char*)As + byte) = pk;
    }
    int cc = t >> 1, khalf = t & 1;
    #pragma unroll
    for (int j = 0; j < 8; ++j){
      int k0 = khalf*64 + j*8;
      short8v w = *(const short8v*)(Wt + cc*128 + k0);
      int byte = (cc*256 + k0*2) ^ ((cc & 7) << 4);
      *(short8v*)((char*)Bs + byte) = w;
    }
  }
  __syncthreads();
  int w = t >> 6, lane = t & 63;
  f32x4 acc[2][8];
  #pragma unroll
  for (int m=0;m<2;m++)
    #pragma unroll
    for (int n=0;n<8;n++) acc[m][n] = (f32x4){0.f,0.f,0.f,0.f};
  #pragma unroll
  for (int kk = 0; kk < 4; ++kk){
    int ks = kk*32 + (lane>>4)*8;
    short8v a[2], b[8];
    #pragma unroll
    for (int m=0;m<2;m++){
      int row = w*32 + m*16 + (lane & 15);
      int byte = (row*256 + ks*2) ^ ((row & 7) << 4);
      a[m] = *(const short8v*)((const char*)As + byte);
    }
    #pragma unroll
    for (int n=0;n<8;n++){
      int col = n*16 + (lane & 15);
      int byte = (col*256 + ks*2) ^ ((col & 7) << 4);
      b[n] = *(const short8v*)((const char*)Bs + byte);
    }
    #pragma unroll
    for (int m=0;m<2;m++)
      #pragma unroll
      for (int n=0;n<8;n++)
        acc[m][n] = __builtin_amdgcn_mfma_f32_16x16x32_bf16(a[m], b[n], acc[m][n], 0, 0, 0);
  }
  #pragma unroll
  for (int m=0;m<2;m++){
    int row_base = brow + w*32 + m*16 + ((lane>>4)<<2);
    #pragma unroll
    for (int r=0;r<4;r++){
      int grow = row_base + r;
      if (grow < N_NODES){
        #pragma unroll
        for (int n=0;n<8;n++)
          Z[(unsigned)grow*128u + n*16 + (lane&15)] = f2bf(acc[m][n][r]);
      }
    }
  }
}

// ---------------- el/er: per (node, head) dot over O=16 ----------------
__global__ void eler_kernel(const unsigned short* __restrict__ Z,
                            const float* __restrict__ al, const float* __restrict__ ar,
                            float* __restrict__ el, float* __restrict__ er)
{
  int t = blockIdx.x*256 + threadIdx.x;
  if (t >= N_NODES*NHEAD) return;
  int h = t & 7;
  const unsigned short* zp = Z + (unsigned)(t>>3)*128u + h*16;
  short8v z0 = *(const short8v*)(zp);
  short8v z1 = *(const short8v*)(zp + 8);
  float sl = 0.f, sr = 0.f;
  #pragma unroll
  for (int o = 0; o < 8; ++o){
    float zv = bf2f((unsigned short)z0[o]);
    sl += zv * al[h*16+o]; sr += zv * ar[h*16+o];
  }
  #pragma unroll
  for (int o = 0; o < 8; ++o){
    float zv = bf2f((unsigned short)z1[o]);
    sl += zv * al[h*16+8+o]; sr += zv * ar[h*16+8+o];
  }
  el[t] = sl; er[t] = sr;
}

// ---------------- per-node attention aggregate + residual + bias (+act) ----------------
__global__ __launch_bounds__(256) void edge_agg(
    const unsigned short* __restrict__ Z, const float* __restrict__ el,
    const float* __restrict__ er, const int* __restrict__ off,
    const int* __restrict__ csr, const unsigned short* __restrict__ Hin,
    const float* __restrict__ bias, unsigned short* __restrict__ Hout,
    int activate)
{
  int tid  = threadIdx.x;
  int lane = tid & 63;
  int n    = __builtin_amdgcn_readfirstlane((int)(blockIdx.x*4 + (tid >> 6)));
  if (n >= N_NODES) return;
  int head = lane >> 3;

  int lo = off[n], hi = off[n+1];
  float ern = er[(unsigned)n*8u + head];
  float acc0a=0.f, acc0b=0.f, acc1a=0.f, acc1b=0.f, sacca=0.f, saccb=0.f;
  const unsigned lidx = (unsigned)(lane*2);          // ushort index within row

  for (int base = lo; base < hi; base += 16){
    int s[16]; float x[16]; unsigned zz[16]; float wv[16];
    #pragma unroll
    for (int j=0;j<16;++j){
      int idx = base + j;
      s[j] = csr[idx < hi ? idx : hi-1];
    }
    #pragma unroll
    for (int j=0;j<16;++j) x[j] = el[(unsigned)s[j]*8u + head] + ern;
    #pragma unroll
    for (int j=0;j<16;++j) zz[j] = *(const unsigned*)(Z + (unsigned)s[j]*128u + lidx);
    #pragma unroll
    for (int j=0;j<16;++j){
      float xv = fmaxf(x[j], 0.2f*x[j]);             // leaky_relu 0.2
      wv[j] = (base + j < hi) ? __expf(xv) : 0.f;    // masked (no max-shift: |e|<<1)
    }
    #pragma unroll
    for (int j=0;j<16;j+=2){
      sacca += wv[j];           saccb += wv[j+1];
      acc0a += wv[j]*lo16f(zz[j]);   acc0b += wv[j+1]*lo16f(zz[j+1]);
      acc1a += wv[j]*hi16f(zz[j]);   acc1b += wv[j+1]*hi16f(zz[j+1]);
    }
  }
  float sacc = sacca + saccb;
  float acc0 = acc0a + acc0b;
  float acc1 = acc1a + acc1b;
  float inv = (hi > lo) ? (1.f / sacc) : 0.f;
  unsigned hv = *(const unsigned*)(Hin + (unsigned)n*128u + lidx);
  int d = lane*2;
  float r0 = acc0*inv + lo16f(hv) + bias[d];
  float r1 = acc1*inv + hi16f(hv) + bias[d+1];
  if (activate){
    r0 = (r0 > 0.f) ? r0 : 0.01f*r0;
    r1 = (r1 > 0.f) ? r1 : 0.01f*r1;
  }
  unsigned outv = ((unsigned)f2bf(r1) << 16) | (unsigned)f2bf(r0);
  *(unsigned*)(Hout + (unsigned)n*128u + lidx) = outv;
}

// ---------------- L2 normalize + gather out = v[x] ----------------
__global__ __launch_bounds__(256) void norm_gather(const unsigned short* __restrict__ H,
    const int* __restrict__ x, float* __restrict__ out)
{
  int row = blockIdx.x*4 + (threadIdx.x >> 6);
  if (row >= BT) return;
  int lane = threadIdx.x & 63;
  unsigned xi = (unsigned)x[row];
  unsigned hv = *(const unsigned*)(H + xi*128u + (unsigned)(lane*2));
  float v0 = lo16f(hv), v1 = hi16f(hv);
  float ss = v0*v0 + v1*v1;
  #pragma unroll
  for (int m = 32; m; m >>= 1) ss += __shfl_xor(ss, m, 64);
  float sc = 1.f / fmaxf(sqrtf(ss), 1e-5f);
  int d = lane*2;
  out[(size_t)row*128 + d]     = v0*sc;
  out[(size_t)row*128 + d + 1] = v1*sc;
}

extern "C" void kernel_launch(void* const* d_in, const int* in_sizes, int n_in,
                              void* d_out, int out_size, void* d_ws, size_t ws_size,
                              hipStream_t stream)
{
  const float* emb = (const float*)d_in[0];
  const float* W0  = (const float*)d_in[1];
  const float* al0 = (const float*)d_in[2];
  const float* ar0 = (const float*)d_in[3];
  const float* b0  = (const float*)d_in[4];
  const float* W1  = (const float*)d_in[5];
  const float* al1 = (const float*)d_in[6];
  const float* ar1 = (const float*)d_in[7];
  const float* b1  = (const float*)d_in[8];
  const int* n_feat = (const int*)d_in[9];
  const int* srcv = (const int*)d_in[10];
  const int* dstv = (const int*)d_in[11];
  const int* xv   = (const int*)d_in[12];
  float* out = (float*)d_out;

  char* p = (char*)d_ws;
  auto alloc = [&](size_t b)->char*{ char* q = p; p += (b + 255) & ~(size_t)255; return q; };
  unsigned short* Z   = (unsigned short*)alloc((size_t)N_NODES*128*2);
  unsigned short* H1b = (unsigned short*)alloc((size_t)N_NODES*128*2);  // layer0 out, layer1 in/out
  unsigned short* Hb0 = (unsigned short*)alloc((size_t)N_NODES*128*2);  // bf16 gathered emb rows
  int* offs  = (int*)alloc((size_t)(N_NODES+1)*4);
  int* csr   = (int*)alloc((size_t)N_EDGES*4);
  unsigned* ebuf = (unsigned*)alloc((size_t)N_EDGES*4);  // dead after p2fine; reused for el/er
  int* bh    = (int*)alloc((size_t)NBKT*NCHUNK*4);
  int* bsum  = (int*)alloc(256*4);
  unsigned short* Wt0 = (unsigned short*)alloc(128*128*2);
  unsigned short* Wt1 = (unsigned short*)alloc(128*128*2);
  float* el = (float*)ebuf;                              // N*8 floats
  float* er = el + (size_t)N_NODES*8;                    // N*8 floats (2*N*8*4 == E*4)

  const int NSCAN = NBKT*NCHUNK;                         // 57344

  // CSR build (no global atomics)
  p1hist<<<NCHUNK, 256, 0, stream>>>(dstv, bh);
  scan_partial<<<NSCAN/256, 256, 0, stream>>>(bh, bh, bsum, NSCAN);
  scan_add2<<<NSCAN/256, 256, 0, stream>>>(bh, bsum, NSCAN/256, NSCAN);
  p1scat<<<NCHUNK, 256, 0, stream>>>(srcv, dstv, bh, ebuf);
  p2fine<<<NBKT, 256, 0, stream>>>(ebuf, bh, offs, csr);

  twt_kernel<<<128, 256, 0, stream>>>(W0, W1, Wt0, Wt1);

  int gemm_grid = (N_NODES + 127)/128;
  int agg_grid  = (N_NODES + 3)/4;
  int eler_grid = (N_NODES*8 + 255)/256;

  // layer 0 (rows gathered emb[n_feat] -> also Hb0; activation on)
  gemm_nt<0><<<gemm_grid, 256, 0, stream>>>(emb, n_feat, Wt0, Z, Hb0);
  eler_kernel<<<eler_grid, 256, 0, stream>>>(Z, al0, ar0, el, er);
  edge_agg<<<agg_grid, 256, 0, stream>>>(Z, el, er, offs, csr, Hb0, b0, H1b, 1);
  // layer 1 (bf16 input; in-place residual safe: wave reads row n before writing it)
  gemm_nt<1><<<gemm_grid, 256, 0, stream>>>(H1b, nullptr, Wt1, Z, nullptr);
  eler_kernel<<<eler_grid, 256, 0, stream>>>(Z, al1, ar1, el, er);
  edge_agg<<<agg_grid, 256, 0, stream>>>(Z, el, er, offs, csr, H1b, b1, H1b, 0);
  // normalize + output gather
  norm_gather<<<(BT + 3)/4, 256, 0, stream>>>(H1b, xv, out);
}

// Round 9
// 171.269 us; speedup vs baseline: 1.2717x; 1.0684x over previous
//
#include <hip/hip_runtime.h>

#define N_NODES 57254
#define N_EDGES 916064
#define DIM 128
#define NHEAD 8
#define BT (64*512)
#define NBKT 224                 // dst>>8 buckets (57254>>8 == 223)
#define NCHUNK 256
#define CHUNK 3579               // ceil(916064/256)

typedef __attribute__((ext_vector_type(8))) short short8v;
typedef __attribute__((ext_vector_type(4))) float f32x4;
typedef __attribute__((ext_vector_type(2))) float f32x2;

#if defined(__has_builtin)
#  if __has_builtin(__builtin_amdgcn_cvt_pk_f32_fp8) && __has_builtin(__builtin_amdgcn_cvt_pk_fp8_f32)
#    define USE_FP8 1
#  endif
#endif
#ifndef USE_FP8
#  define USE_FP8 0
#endif

#define ZSCALE 16.0f
#define ZSCALE_INV (1.0f/16.0f)

static __device__ __forceinline__ unsigned short f2bf(float f){
  unsigned int b = __builtin_bit_cast(unsigned int, f);
  b += 0x7fffu + ((b >> 16) & 1u);           // round-to-nearest-even
  return (unsigned short)(b >> 16);
}
static __device__ __forceinline__ float bf2f(unsigned short u){
  unsigned int b = ((unsigned int)u) << 16;
  return __builtin_bit_cast(float, b);
}
static __device__ __forceinline__ float lo16f(unsigned int zz){
  return __builtin_bit_cast(float, zz << 16);
}
static __device__ __forceinline__ float hi16f(unsigned int zz){
  return __builtin_bit_cast(float, zz & 0xffff0000u);
}

// Z element IO: fp8 (1B) if available, else bf16 (2B)
#if USE_FP8
#define ZB 1
static __device__ __forceinline__ void z_store(unsigned char* Zp, float v){
  unsigned u = (unsigned)__builtin_amdgcn_cvt_pk_fp8_f32(v*ZSCALE, v*ZSCALE, 0, false);
  *Zp = (unsigned char)(u & 0xffu);
}
static __device__ __forceinline__ f32x2 z_pair(unsigned short w){  // 2 consecutive dims
  return __builtin_amdgcn_cvt_pk_f32_fp8((int)(unsigned)w, false); // *ZSCALE_INV deferred
}
#else
#define ZB 2
static __device__ __forceinline__ void z_store(unsigned char* Zp, float v){
  *(unsigned short*)Zp = f2bf(v);
}
static __device__ __forceinline__ f32x2 z_pair(unsigned zz){
  f32x2 r; r.x = lo16f(zz)*ZSCALE; r.y = hi16f(zz)*ZSCALE; return r;
}
#endif

// ---------------- CSR build: two-level counting sort, no global atomics ----------------

__global__ __launch_bounds__(256) void p1hist(const int* __restrict__ dst,
                                              int* __restrict__ bh){
  __shared__ int h[NBKT];
  int t = threadIdx.x, c = blockIdx.x;
  if (t < NBKT) h[t] = 0;
  __syncthreads();
  int lo = c*CHUNK, hi = lo + CHUNK; if (hi > N_EDGES) hi = N_EDGES;
  for (int i = lo + t; i < hi; i += 256)
    atomicAdd(&h[((unsigned)dst[i]) >> 8], 1);
  __syncthreads();
  if (t < NBKT) bh[t*NCHUNK + c] = h[t];     // bucket-major layout for scan
}

__global__ void scan_partial(const int* __restrict__ in, int* __restrict__ out,
                             int* __restrict__ bsum, int n){
  __shared__ int sm[256];
  int tid = threadIdx.x;
  int i = blockIdx.x*256 + tid;
  int v = (i < n) ? in[i] : 0;
  sm[tid] = v;
  __syncthreads();
  #pragma unroll
  for (int d = 1; d < 256; d <<= 1){
    int add = (tid >= d) ? sm[tid - d] : 0;
    __syncthreads();
    sm[tid] += add;
    __syncthreads();
  }
  if (i < n) out[i] = sm[tid] - v;
  if (tid == 255) bsum[blockIdx.x] = sm[255];
}

// block b adds sum(bsum[0..b)) to its 256 elements
__global__ void scan_add2(int* __restrict__ out, const int* __restrict__ bsum,
                          int nb, int n){
  __shared__ int sm[256];
  int t = threadIdx.x, b = blockIdx.x;
  sm[t] = (t < b && t < nb) ? bsum[t] : 0;
  __syncthreads();
  #pragma unroll
  for (int d = 128; d; d >>= 1){
    if (t < d) sm[t] += sm[t + d];
    __syncthreads();
  }
  int i = b*256 + t;
  if (i < n) out[i] += sm[0];
}

// Phase 1b: LDS-staged coarse scatter. Edge packed as (src<<16)|(dst&255).
__global__ __launch_bounds__(256) void p1scat(const int* __restrict__ src,
                                              const int* __restrict__ dst,
                                              const int* __restrict__ bases,
                                              unsigned* __restrict__ ebuf){
  __shared__ unsigned stage[CHUNK];
  __shared__ short bkt_of[CHUNK];
  __shared__ int lh[256], smm[256], ls[NBKT+1], cur[NBKT], gb[NBKT];
  int t = threadIdx.x, c = blockIdx.x;
  lh[t] = 0;
  __syncthreads();
  int lo = c*CHUNK, hi = lo + CHUNK; if (hi > N_EDGES) hi = N_EDGES;
  int len = hi - lo;
  for (int i = lo + t; i < hi; i += 256)
    atomicAdd(&lh[((unsigned)dst[i]) >> 8], 1);
  __syncthreads();
  int v = lh[t];
  smm[t] = v;
  __syncthreads();
  #pragma unroll
  for (int d = 1; d < 256; d <<= 1){
    int add = (t >= d) ? smm[t - d] : 0;
    __syncthreads();
    smm[t] += add;
    __syncthreads();
  }
  if (t < NBKT){ ls[t] = smm[t] - v; cur[t] = smm[t] - v; gb[t] = bases[t*NCHUNK + c]; }
  if (t == 255) ls[NBKT] = smm[255];          // == len
  __syncthreads();
  if (t < NBKT){
    int e0 = ls[t], e1 = ls[t+1];
    for (int k = e0; k < e1; ++k) bkt_of[k] = (short)t;
  }
  __syncthreads();
  for (int i = lo + t; i < hi; i += 256){
    unsigned d = (unsigned)dst[i];
    int b = d >> 8;
    int pos = atomicAdd(&cur[b], 1);
    stage[pos] = (((unsigned)src[i]) << 16) | (d & 255u);
  }
  __syncthreads();
  for (int k = t; k < len; k += 256){
    int b = bkt_of[k];
    ebuf[gb[b] + (k - ls[b])] = stage[k];
  }
}

// Phase 2: per-bucket fine sort -> offs + csr
__global__ __launch_bounds__(256) void p2fine(const unsigned* __restrict__ ebuf,
                                              const int* __restrict__ bases,
                                              int* __restrict__ offs,
                                              int* __restrict__ csr){
  __shared__ int cnt[256], sm[256], loff[256], cur[256];
  int t = threadIdx.x, b = blockIdx.x;
  int bstart = bases[b*NCHUNK];
  int bend   = (b < NBKT-1) ? bases[(b+1)*NCHUNK] : N_EDGES;
  cnt[t] = 0;
  __syncthreads();
  for (int i = bstart + t; i < bend; i += 256)
    atomicAdd(&cnt[ebuf[i] & 255u], 1);
  __syncthreads();
  int v = cnt[t];
  sm[t] = v;
  __syncthreads();
  #pragma unroll
  for (int d = 1; d < 256; d <<= 1){
    int add = (t >= d) ? sm[t - d] : 0;
    __syncthreads();
    sm[t] += add;
    __syncthreads();
  }
  loff[t] = sm[t] - v;
  cur[t]  = bstart + sm[t] - v;
  int nlo = b*256;
  int nn  = N_NODES - nlo; if (nn > 256) nn = 256;
  if (t < nn) offs[nlo + t] = bstart + loff[t];
  if (b == NBKT-1 && t == 0) offs[N_NODES] = N_EDGES;
  __syncthreads();
  for (int i = bstart + t; i < bend; i += 256){
    unsigned e = ebuf[i];
    int pos = atomicAdd(&cur[e & 255u], 1);
    csr[pos] = (int)(e >> 16);
  }
}

// ---------------- W transpose -> bf16 Wt[c][k], both layers in one launch ----------------
__global__ void twt_kernel(const float* __restrict__ W0, const float* __restrict__ W1,
                           unsigned short* __restrict__ Wt0, unsigned short* __restrict__ Wt1){
  int t = blockIdx.x*256 + threadIdx.x;   // 0..32767
  int which = t >> 14;
  int i = t & 16383;
  int c = i >> 7, k = i & 127;
  const float* W = which ? W1 : W0;
  unsigned short* Wt = which ? Wt1 : Wt0;
  Wt[i] = f2bf(W[k*128 + c]);
}

// ---------------- GEMM: Z = A @ W (128x128 tile, A+B in LDS) ----------------
// MODE 0: A f32 + row-gather (also emits Hb bf16 copy). MODE 1: A bf16 contiguous.
// Z stored as fp8 (x16) when available.
template<int MODE>
__global__ __launch_bounds__(256) void gemm_nt(
    const void* __restrict__ Av, const int* __restrict__ gidx,
    const unsigned short* __restrict__ Wt,   // bf16 [col][k]
    unsigned char* __restrict__ Z,           // [N][128] fp8 (or bf16 if !USE_FP8)
    unsigned short* __restrict__ Hb)
{
  __shared__ unsigned short As[128*128];     // 32KB
  __shared__ unsigned short Bs[128*128];     // 32KB
  int t = threadIdx.x;
  int brow = blockIdx.x * 128;
  {
    int r = t >> 1, half = t & 1;
    int grow = brow + r;
    bool valid = grow < N_NODES;
    unsigned srcr = 0u;
    if (MODE == 0) srcr = valid ? (unsigned)gidx[grow] : 0u;
    #pragma unroll
    for (int j = 0; j < 8; ++j){
      int c = half*64 + j*8;
      short8v pk;
      if (MODE == 0){
        const float* arow = (const float*)Av + (size_t)srcr * DIM;
        float4 a0, a1;
        if (valid){ a0 = *(const float4*)(arow + c); a1 = *(const float4*)(arow + c + 4); }
        else { a0 = make_float4(0.f,0.f,0.f,0.f); a1 = a0; }
        pk[0]=(short)f2bf(a0.x); pk[1]=(short)f2bf(a0.y); pk[2]=(short)f2bf(a0.z); pk[3]=(short)f2bf(a0.w);
        pk[4]=(short)f2bf(a1.x); pk[5]=(short)f2bf(a1.y); pk[6]=(short)f2bf(a1.z); pk[7]=(short)f2bf(a1.w);
        if (valid) *(short8v*)(Hb + (unsigned)grow*128u + c) = pk;
      } else {
        const unsigned short* A = (const unsigned short*)Av;
        if (valid) pk = *(const short8v*)(A + (unsigned)grow*128u + c);
        else       pk = (short8v){0,0,0,0,0,0,0,0};
      }
      int byte = (r*256 + c*2) ^ ((r & 7) << 4);
      *(short8v*)((char*)As + byte) = pk;
    }
    int cc = t >> 1, khalf = t & 1;
    #pragma unroll
    for (int j = 0; j < 8; ++j){
      int k0 = khalf*64 + j*8;
      short8v w = *(const short8v*)(Wt + cc*128 + k0);
      int byte = (cc*256 + k0*2) ^ ((cc & 7) << 4);
      *(short8v*)((char*)Bs + byte) = w;
    }
  }
  __syncthreads();
  int w = t >> 6, lane = t & 63;
  f32x4 acc[2][8];
  #pragma unroll
  for (int m=0;m<2;m++)
    #pragma unroll
    for (int n=0;n<8;n++) acc[m][n] = (f32x4){0.f,0.f,0.f,0.f};
  #pragma unroll
  for (int kk = 0; kk < 4; ++kk){
    int ks = kk*32 + (lane>>4)*8;
    short8v a[2], b[8];
    #pragma unroll
    for (int m=0;m<2;m++){
      int row = w*32 + m*16 + (lane & 15);
      int byte = (row*256 + ks*2) ^ ((row & 7) << 4);
      a[m] = *(const short8v*)((const char*)As + byte);
    }
    #pragma unroll
    for (int n=0;n<8;n++){
      int col = n*16 + (lane & 15);
      int byte = (col*256 + ks*2) ^ ((col & 7) << 4);
      b[n] = *(const short8v*)((const char*)Bs + byte);
    }
    #pragma unroll
    for (int m=0;m<2;m++)
      #pragma unroll
      for (int n=0;n<8;n++)
        acc[m][n] = __builtin_amdgcn_mfma_f32_16x16x32_bf16(a[m], b[n], acc[m][n], 0, 0, 0);
  }
  #pragma unroll
  for (int m=0;m<2;m++){
    int row_base = brow + w*32 + m*16 + ((lane>>4)<<2);
    #pragma unroll
    for (int r=0;r<4;r++){
      int grow = row_base + r;
      if (grow < N_NODES){
        #pragma unroll
        for (int n=0;n<8;n++)
          z_store(Z + ((unsigned)grow*128u + n*16 + (lane&15))*ZB, acc[m][n][r]);
      }
    }
  }
}

// ---------------- el/er: per (node, head) dot over O=16; el bf16, er f32 ----------------
__global__ void eler_kernel(const unsigned char* __restrict__ Z,
                            const float* __restrict__ al, const float* __restrict__ ar,
                            unsigned short* __restrict__ el, float* __restrict__ er)
{
  int t = blockIdx.x*256 + threadIdx.x;
  if (t >= N_NODES*NHEAD) return;
  int h = t & 7;
  const unsigned char* zp = Z + ((unsigned)(t>>3)*128u + h*16)*ZB;
  float zv[16];
#if USE_FP8
  uint4 zw = *(const uint4*)zp;
  f32x2 p;
  p = z_pair((unsigned short)(zw.x & 0xffffu));      zv[0]=p.x;  zv[1]=p.y;
  p = __builtin_amdgcn_cvt_pk_f32_fp8((int)zw.x, true);  zv[2]=p.x;  zv[3]=p.y;
  p = z_pair((unsigned short)(zw.y & 0xffffu));      zv[4]=p.x;  zv[5]=p.y;
  p = __builtin_amdgcn_cvt_pk_f32_fp8((int)zw.y, true);  zv[6]=p.x;  zv[7]=p.y;
  p = z_pair((unsigned short)(zw.z & 0xffffu));      zv[8]=p.x;  zv[9]=p.y;
  p = __builtin_amdgcn_cvt_pk_f32_fp8((int)zw.z, true);  zv[10]=p.x; zv[11]=p.y;
  p = z_pair((unsigned short)(zw.w & 0xffffu));      zv[12]=p.x; zv[13]=p.y;
  p = __builtin_amdgcn_cvt_pk_f32_fp8((int)zw.w, true);  zv[14]=p.x; zv[15]=p.y;
#else
  short8v z0 = *(const short8v*)(zp);
  short8v z1 = *(const short8v*)(zp + 16);
  #pragma unroll
  for (int o = 0; o < 8; ++o){ zv[o] = bf2f((unsigned short)z0[o])*ZSCALE; zv[8+o] = bf2f((unsigned short)z1[o])*ZSCALE; }
#endif
  float sl = 0.f, sr = 0.f;
  #pragma unroll
  for (int o = 0; o < 16; ++o){
    sl += zv[o] * al[h*16+o]; sr += zv[o] * ar[h*16+o];
  }
  el[t] = f2bf(sl*ZSCALE_INV); er[t] = sr*ZSCALE_INV;
}

// ---------------- per-node attention aggregate + residual + bias (+act) ----------------
__global__ __launch_bounds__(256) void edge_agg(
    const unsigned char* __restrict__ Z, const unsigned short* __restrict__ el,
    const float* __restrict__ er, const int* __restrict__ off,
    const int* __restrict__ csr, const unsigned short* __restrict__ Hin,
    const float* __restrict__ bias, unsigned short* __restrict__ Hout,
    int activate)
{
  int tid  = threadIdx.x;
  int lane = tid & 63;
  int n    = __builtin_amdgcn_readfirstlane((int)(blockIdx.x*4 + (tid >> 6)));
  if (n >= N_NODES) return;
  int head = lane >> 3;

  int lo = off[n], hi = off[n+1];
  float ern = er[(unsigned)n*8u + head];
  float acc0a=0.f, acc0b=0.f, acc1a=0.f, acc1b=0.f, sacca=0.f, saccb=0.f;
  const unsigned lidx = (unsigned)(lane*2);          // dim index (2 dims/lane)

  for (int base = lo; base < hi; base += 16){
    int s[16]; float x[16]; unsigned short zz[16]; float wv[16];
    #pragma unroll
    for (int j=0;j<16;++j){
      int idx = base + j;
      s[j] = csr[idx < hi ? idx : hi-1];
    }
    #pragma unroll
    for (int j=0;j<16;++j) x[j] = bf2f(el[(unsigned)s[j]*8u + head]) + ern;
    #pragma unroll
    for (int j=0;j<16;++j) zz[j] = *(const unsigned short*)(Z + ((unsigned)s[j]*128u + lidx)*ZB);
    #pragma unroll
    for (int j=0;j<16;++j){
      float xv = fmaxf(x[j], 0.2f*x[j]);             // leaky_relu 0.2
      wv[j] = (base + j < hi) ? __expf(xv) : 0.f;    // masked (no max-shift: |e|<<1)
    }
    #pragma unroll
    for (int j=0;j<16;j+=2){
      f32x2 z0 = z_pair(zz[j]);
      f32x2 z1 = z_pair(zz[j+1]);
      sacca += wv[j];        saccb += wv[j+1];
      acc0a += wv[j]*z0.x;   acc0b += wv[j+1]*z1.x;
      acc1a += wv[j]*z0.y;   acc1b += wv[j+1]*z1.y;
    }
  }
  float sacc = sacca + saccb;
  float acc0 = acc0a + acc0b;
  float acc1 = acc1a + acc1b;
  float inv = (hi > lo) ? (ZSCALE_INV / sacc) : 0.f; // fold fp8 x16 scale out
  unsigned hv = *(const unsigned*)(Hin + (unsigned)n*128u + lidx);
  int d = lane*2;
  float r0 = acc0*inv + lo16f(hv) + bias[d];
  float r1 = acc1*inv + hi16f(hv) + bias[d+1];
  if (activate){
    r0 = (r0 > 0.f) ? r0 : 0.01f*r0;
    r1 = (r1 > 0.f) ? r1 : 0.01f*r1;
  }
  unsigned outv = ((unsigned)f2bf(r1) << 16) | (unsigned)f2bf(r0);
  *(unsigned*)(Hout + (unsigned)n*128u + lidx) = outv;
}

// ---------------- L2 normalize + gather out = v[x] ----------------
__global__ __launch_bounds__(256) void norm_gather(const unsigned short* __restrict__ H,
    const int* __restrict__ x, float* __restrict__ out)
{
  int row = blockIdx.x*4 + (threadIdx.x >> 6);
  if (row >= BT) return;
  int lane = threadIdx.x & 63;
  unsigned xi = (unsigned)x[row];
  unsigned hv = *(const unsigned*)(H + xi*128u + (unsigned)(lane*2));
  float v0 = lo16f(hv), v1 = hi16f(hv);
  float ss = v0*v0 + v1*v1;
  #pragma unroll
  for (int m = 32; m; m >>= 1) ss += __shfl_xor(ss, m, 64);
  float sc = 1.f / fmaxf(sqrtf(ss), 1e-5f);
  int d = lane*2;
  out[(size_t)row*128 + d]     = v0*sc;
  out[(size_t)row*128 + d + 1] = v1*sc;
}

extern "C" void kernel_launch(void* const* d_in, const int* in_sizes, int n_in,
                              void* d_out, int out_size, void* d_ws, size_t ws_size,
                              hipStream_t stream)
{
  const float* emb = (const float*)d_in[0];
  const float* W0  = (const float*)d_in[1];
  const float* al0 = (const float*)d_in[2];
  const float* ar0 = (const float*)d_in[3];
  const float* b0  = (const float*)d_in[4];
  const float* W1  = (const float*)d_in[5];
  const float* al1 = (const float*)d_in[6];
  const float* ar1 = (const float*)d_in[7];
  const float* b1  = (const float*)d_in[8];
  const int* n_feat = (const int*)d_in[9];
  const int* srcv = (const int*)d_in[10];
  const int* dstv = (const int*)d_in[11];
  const int* xv   = (const int*)d_in[12];
  float* out = (float*)d_out;

  char* p = (char*)d_ws;
  auto alloc = [&](size_t b)->char*{ char* q = p; p += (b + 255) & ~(size_t)255; return q; };
  unsigned char*  Z   = (unsigned char*)alloc((size_t)N_NODES*128*ZB);
  unsigned short* H1b = (unsigned short*)alloc((size_t)N_NODES*128*2);  // layer0 out, layer1 in/out
  unsigned short* Hb0 = (unsigned short*)alloc((size_t)N_NODES*128*2);  // bf16 gathered emb rows
  int* offs  = (int*)alloc((size_t)(N_NODES+1)*4);
  int* csr   = (int*)alloc((size_t)N_EDGES*4);
  unsigned* ebuf = (unsigned*)alloc((size_t)N_EDGES*4);  // dead after p2fine; reused for el/er
  int* bh    = (int*)alloc((size_t)NBKT*NCHUNK*4);
  int* bsum  = (int*)alloc(256*4);
  unsigned short* Wt0 = (unsigned short*)alloc(128*128*2);
  unsigned short* Wt1 = (unsigned short*)alloc(128*128*2);
  unsigned short* el = (unsigned short*)ebuf;            // N*8 bf16 (0.9 MB)
  float* er = (float*)(((char*)ebuf) + (((size_t)N_NODES*8*2 + 255) & ~(size_t)255)); // N*8 f32

  const int NSCAN = NBKT*NCHUNK;                         // 57344

  // CSR build (no global atomics)
  p1hist<<<NCHUNK, 256, 0, stream>>>(dstv, bh);
  scan_partial<<<NSCAN/256, 256, 0, stream>>>(bh, bh, bsum, NSCAN);
  scan_add2<<<NSCAN/256, 256, 0, stream>>>(bh, bsum, NSCAN/256, NSCAN);
  p1scat<<<NCHUNK, 256, 0, stream>>>(srcv, dstv, bh, ebuf);
  p2fine<<<NBKT, 256, 0, stream>>>(ebuf, bh, offs, csr);

  twt_kernel<<<128, 256, 0, stream>>>(W0, W1, Wt0, Wt1);

  int gemm_grid = (N_NODES + 127)/128;
  int agg_grid  = (N_NODES + 3)/4;
  int eler_grid = (N_NODES*8 + 255)/256;

  // layer 0 (rows gathered emb[n_feat] -> also Hb0; activation on)
  gemm_nt<0><<<gemm_grid, 256, 0, stream>>>(emb, n_feat, Wt0, Z, Hb0);
  eler_kernel<<<eler_grid, 256, 0, stream>>>(Z, al0, ar0, el, er);
  edge_agg<<<agg_grid, 256, 0, stream>>>(Z, el, er, offs, csr, Hb0, b0, H1b, 1);
  // layer 1 (bf16 input; in-place residual safe: wave reads row n before writing it)
  gemm_nt<1><<<gemm_grid, 256, 0, stream>>>(H1b, nullptr, Wt1, Z, nullptr);
  eler_kernel<<<eler_grid, 256, 0, stream>>>(Z, al1, ar1, el, er);
  edge_agg<<<agg_grid, 256, 0, stream>>>(Z, el, er, offs, csr, H1b, b1, H1b, 0);
  // normalize + output gather
  norm_gather<<<(BT + 3)/4, 256, 0, stream>>>(H1b, xv, out);
}

// Round 11
// 160.247 us; speedup vs baseline: 1.3592x; 1.0688x over previous
//
#include <hip/hip_runtime.h>

#define N_NODES 57254
#define N_EDGES 916064
#define DIM 128
#define NHEAD 8
#define BT (64*512)
#define NBKT 224                 // dst>>8 buckets (57254>>8 == 223)
#define NCHUNK 256
#define CHUNK 3579               // ceil(916064/256)
#define LOG2E 1.4426950408889634f

typedef __attribute__((ext_vector_type(8))) short short8v;
typedef __attribute__((ext_vector_type(4))) float f32x4;
typedef __attribute__((ext_vector_type(2))) float f32x2;

#if defined(__has_builtin)
#  if __has_builtin(__builtin_amdgcn_cvt_pk_f32_fp8) && __has_builtin(__builtin_amdgcn_cvt_pk_fp8_f32)
#    define USE_FP8 1
#  endif
#endif
#ifndef USE_FP8
#  define USE_FP8 0
#endif

#define ZSCALE 16.0f
#define ZSCALE_INV (1.0f/16.0f)

static __device__ __forceinline__ unsigned short f2bf(float f){
  unsigned int b = __builtin_bit_cast(unsigned int, f);
  b += 0x7fffu + ((b >> 16) & 1u);           // round-to-nearest-even
  return (unsigned short)(b >> 16);
}
static __device__ __forceinline__ float bf2f(unsigned short u){
  unsigned int b = ((unsigned int)u) << 16;
  return __builtin_bit_cast(float, b);
}
static __device__ __forceinline__ float lo16f(unsigned int zz){
  return __builtin_bit_cast(float, zz << 16);
}
static __device__ __forceinline__ float hi16f(unsigned int zz){
  return __builtin_bit_cast(float, zz & 0xffff0000u);
}

// Z element IO: fp8 (1B) if available, else bf16 (2B)
#if USE_FP8
#define ZB 1
static __device__ __forceinline__ void z_store(unsigned char* Zp, float v){
  unsigned u = (unsigned)__builtin_amdgcn_cvt_pk_fp8_f32(v*ZSCALE, v*ZSCALE, 0, false);
  *Zp = (unsigned char)(u & 0xffu);
}
static __device__ __forceinline__ f32x2 z_pair(unsigned short w){  // 2 consecutive dims
  return __builtin_amdgcn_cvt_pk_f32_fp8((int)(unsigned)w, false); // *ZSCALE_INV deferred
}
#else
#define ZB 2
static __device__ __forceinline__ void z_store(unsigned char* Zp, float v){
  *(unsigned short*)Zp = f2bf(v);
}
static __device__ __forceinline__ f32x2 z_pair(unsigned zz){
  f32x2 r; r.x = lo16f(zz)*ZSCALE; r.y = hi16f(zz)*ZSCALE; return r;
}
#endif

// ---------------- CSR build: two-level counting sort, no global atomics ----------------

__global__ __launch_bounds__(256) void p1hist(const int* __restrict__ dst,
                                              int* __restrict__ bh){
  __shared__ int h[NBKT];
  int t = threadIdx.x, c = blockIdx.x;
  if (t < NBKT) h[t] = 0;
  __syncthreads();
  int lo = c*CHUNK, hi = lo + CHUNK; if (hi > N_EDGES) hi = N_EDGES;
  for (int i = lo + t; i < hi; i += 256)
    atomicAdd(&h[((unsigned)dst[i]) >> 8], 1);
  __syncthreads();
  if (t < NBKT) bh[t*NCHUNK + c] = h[t];     // bucket-major layout for scan
}

__global__ void scan_partial(const int* __restrict__ in, int* __restrict__ out,
                             int* __restrict__ bsum, int n){
  __shared__ int sm[256];
  int tid = threadIdx.x;
  int i = blockIdx.x*256 + tid;
  int v = (i < n) ? in[i] : 0;
  sm[tid] = v;
  __syncthreads();
  #pragma unroll
  for (int d = 1; d < 256; d <<= 1){
    int add = (tid >= d) ? sm[tid - d] : 0;
    __syncthreads();
    sm[tid] += add;
    __syncthreads();
  }
  if (i < n) out[i] = sm[tid] - v;
  if (tid == 255) bsum[blockIdx.x] = sm[255];
}

// block b adds sum(bsum[0..b)) to its 256 elements
__global__ void scan_add2(int* __restrict__ out, const int* __restrict__ bsum,
                          int nb, int n){
  __shared__ int sm[256];
  int t = threadIdx.x, b = blockIdx.x;
  sm[t] = (t < b && t < nb) ? bsum[t] : 0;
  __syncthreads();
  #pragma unroll
  for (int d = 128; d; d >>= 1){
    if (t < d) sm[t] += sm[t + d];
    __syncthreads();
  }
  int i = b*256 + t;
  if (i < n) out[i] += sm[0];
}

// Phase 1b: LDS-staged coarse scatter. Edge packed as (src<<16)|(dst&255).
__global__ __launch_bounds__(256) void p1scat(const int* __restrict__ src,
                                              const int* __restrict__ dst,
                                              const int* __restrict__ bases,
                                              unsigned* __restrict__ ebuf){
  __shared__ unsigned stage[CHUNK];
  __shared__ short bkt_of[CHUNK];
  __shared__ int lh[256], smm[256], ls[NBKT+1], cur[NBKT], gb[NBKT];
  int t = threadIdx.x, c = blockIdx.x;
  lh[t] = 0;
  __syncthreads();
  int lo = c*CHUNK, hi = lo + CHUNK; if (hi > N_EDGES) hi = N_EDGES;
  int len = hi - lo;
  for (int i = lo + t; i < hi; i += 256)
    atomicAdd(&lh[((unsigned)dst[i]) >> 8], 1);
  __syncthreads();
  int v = lh[t];
  smm[t] = v;
  __syncthreads();
  #pragma unroll
  for (int d = 1; d < 256; d <<= 1){
    int add = (t >= d) ? smm[t - d] : 0;
    __syncthreads();
    smm[t] += add;
    __syncthreads();
  }
  if (t < NBKT){ ls[t] = smm[t] - v; cur[t] = smm[t] - v; gb[t] = bases[t*NCHUNK + c]; }
  if (t == 255) ls[NBKT] = smm[255];          // == len
  __syncthreads();
  if (t < NBKT){
    int e0 = ls[t], e1 = ls[t+1];
    for (int k = e0; k < e1; ++k) bkt_of[k] = (short)t;
  }
  __syncthreads();
  for (int i = lo + t; i < hi; i += 256){
    unsigned d = (unsigned)dst[i];
    int b = d >> 8;
    int pos = atomicAdd(&cur[b], 1);
    stage[pos] = (((unsigned)src[i]) << 16) | (d & 255u);
  }
  __syncthreads();
  for (int k = t; k < len; k += 256){
    int b = bkt_of[k];
    ebuf[gb[b] + (k - ls[b])] = stage[k];
  }
}

// Phase 2: per-bucket fine sort -> padded offs/pcnt + csr (pad to x8 with DUMMY node)
__global__ __launch_bounds__(256) void p2fine(const unsigned* __restrict__ ebuf,
                                              const int* __restrict__ bases,
                                              int* __restrict__ offs,
                                              int* __restrict__ pcnt,
                                              int* __restrict__ csr){
  __shared__ int cnt[256], sm[256], plo[256], cur[256];
  int t = threadIdx.x, b = blockIdx.x;
  int bstart = bases[b*NCHUNK];
  int bend   = (b < NBKT-1) ? bases[(b+1)*NCHUNK] : N_EDGES;
  int pbstart = bstart + b*1792;               // padded window (<=256 nodes x 7 pad)
  cnt[t] = 0;
  __syncthreads();
  for (int i = bstart + t; i < bend; i += 256)
    atomicAdd(&cnt[ebuf[i] & 255u], 1);
  __syncthreads();
  int v = cnt[t];
  int pv = (v + 7) & ~7;
  sm[t] = pv;
  __syncthreads();
  #pragma unroll
  for (int d = 1; d < 256; d <<= 1){
    int add = (t >= d) ? sm[t - d] : 0;
    __syncthreads();
    sm[t] += add;
    __syncthreads();
  }
  plo[t] = sm[t] - pv;
  cur[t] = pbstart + plo[t];
  int nlo = b*256;
  int nn  = N_NODES - nlo; if (nn > 256) nn = 256;
  if (t < nn){ offs[nlo + t] = pbstart + plo[t]; pcnt[nlo + t] = pv; }
  __syncthreads();
  for (int i = bstart + t; i < bend; i += 256){
    unsigned e = ebuf[i];
    int pos = atomicAdd(&cur[e & 255u], 1);
    csr[pos] = (int)(e >> 16);
  }
  __syncthreads();
  if (t < nn){
    int end = pbstart + plo[t] + pv;
    for (int k = cur[t]; k < end; ++k) csr[k] = N_NODES;   // dummy node
  }
}

// ---------------- W transpose -> bf16 Wt[c][k], both layers in one launch ----------------
__global__ void twt_kernel(const float* __restrict__ W0, const float* __restrict__ W1,
                           unsigned short* __restrict__ Wt0, unsigned short* __restrict__ Wt1){
  int t = blockIdx.x*256 + threadIdx.x;   // 0..32767
  int which = t >> 14;
  int i = t & 16383;
  int c = i >> 7, k = i & 127;
  const float* W = which ? W1 : W0;
  unsigned short* Wt = which ? Wt1 : Wt0;
  Wt[i] = f2bf(W[k*128 + c]);
}

// ---------------- GEMM: Z = A @ W (128x128 tile, A+B in LDS) ----------------
template<int MODE>
__global__ __launch_bounds__(256) void gemm_nt(
    const void* __restrict__ Av, const int* __restrict__ gidx,
    const unsigned short* __restrict__ Wt,   // bf16 [col][k]
    unsigned char* __restrict__ Z,           // [N+1][128] fp8 (or bf16 if !USE_FP8)
    unsigned short* __restrict__ Hb)
{
  __shared__ unsigned short As[128*128];     // 32KB
  __shared__ unsigned short Bs[128*128];     // 32KB
  int t = threadIdx.x;
  int brow = blockIdx.x * 128;
  {
    int r = t >> 1, half = t & 1;
    int grow = brow + r;
    bool valid = grow < N_NODES;
    unsigned srcr = 0u;
    if (MODE == 0) srcr = valid ? (unsigned)gidx[grow] : 0u;
    #pragma unroll
    for (int j = 0; j < 8; ++j){
      int c = half*64 + j*8;
      short8v pk;
      if (MODE == 0){
        const float* arow = (const float*)Av + (size_t)srcr * DIM;
        float4 a0, a1;
        if (valid){ a0 = *(const float4*)(arow + c); a1 = *(const float4*)(arow + c + 4); }
        else { a0 = make_float4(0.f,0.f,0.f,0.f); a1 = a0; }
        pk[0]=(short)f2bf(a0.x); pk[1]=(short)f2bf(a0.y); pk[2]=(short)f2bf(a0.z); pk[3]=(short)f2bf(a0.w);
        pk[4]=(short)f2bf(a1.x); pk[5]=(short)f2bf(a1.y); pk[6]=(short)f2bf(a1.z); pk[7]=(short)f2bf(a1.w);
        if (valid) *(short8v*)(Hb + (unsigned)grow*128u + c) = pk;
      } else {
        const unsigned short* A = (const unsigned short*)Av;
        if (valid) pk = *(const short8v*)(A + (unsigned)grow*128u + c);
        else       pk = (short8v){0,0,0,0,0,0,0,0};
      }
      int byte = (r*256 + c*2) ^ ((r & 7) << 4);
      *(short8v*)((char*)As + byte) = pk;
    }
    int cc = t >> 1, khalf = t & 1;
    #pragma unroll
    for (int j = 0; j < 8; ++j){
      int k0 = khalf*64 + j*8;
      short8v w = *(const short8v*)(Wt + cc*128 + k0);
      int byte = (cc*256 + k0*2) ^ ((cc & 7) << 4);
      *(short8v*)((char*)Bs + byte) = w;
    }
  }
  __syncthreads();
  int w = t >> 6, lane = t & 63;
  f32x4 acc[2][8];
  #pragma unroll
  for (int m=0;m<2;m++)
    #pragma unroll
    for (int n=0;n<8;n++) acc[m][n] = (f32x4){0.f,0.f,0.f,0.f};
  #pragma unroll
  for (int kk = 0; kk < 4; ++kk){
    int ks = kk*32 + (lane>>4)*8;
    short8v a[2], b[8];
    #pragma unroll
    for (int m=0;m<2;m++){
      int row = w*32 + m*16 + (lane & 15);
      int byte = (row*256 + ks*2) ^ ((row & 7) << 4);
      a[m] = *(const short8v*)((const char*)As + byte);
    }
    #pragma unroll
    for (int n=0;n<8;n++){
      int col = n*16 + (lane & 15);
      int byte = (col*256 + ks*2) ^ ((col & 7) << 4);
      b[n] = *(const short8v*)((const char*)Bs + byte);
    }
    #pragma unroll
    for (int m=0;m<2;m++)
      #pragma unroll
      for (int n=0;n<8;n++)
        acc[m][n] = __builtin_amdgcn_mfma_f32_16x16x32_bf16(a[m], b[n], acc[m][n], 0, 0, 0);
  }
  #pragma unroll
  for (int m=0;m<2;m++){
    int row_base = brow + w*32 + m*16 + ((lane>>4)<<2);
    #pragma unroll
    for (int r=0;r<4;r++){
      int grow = row_base + r;
      if (grow < N_NODES){
        #pragma unroll
        for (int n=0;n<8;n++)
          z_store(Z + ((unsigned)grow*128u + n*16 + (lane&15))*ZB, acc[m][n][r]);
      }
    }
  }
}

// ---------------- el/er per (node, head); pre-scaled by log2(e); el bf16, er f32 ----
// Also writes dummy-node el = -inf (node N_NODES).
__global__ void eler_kernel(const unsigned char* __restrict__ Z,
                            const float* __restrict__ al, const float* __restrict__ ar,
                            unsigned short* __restrict__ el, float* __restrict__ er)
{
  int t = blockIdx.x*256 + threadIdx.x;
  if (t >= N_NODES*NHEAD){
    if (t < (N_NODES+1)*NHEAD){ el[t] = 0xFF80u; er[t] = 0.f; }  // -inf bf16
    return;
  }
  int h = t & 7;
  const unsigned char* zp = Z + ((unsigned)(t>>3)*128u + h*16)*ZB;
  float zv[16];
#if USE_FP8
  uint4 zw = *(const uint4*)zp;
  f32x2 p;
  p = z_pair((unsigned short)(zw.x & 0xffffu));      zv[0]=p.x;  zv[1]=p.y;
  p = __builtin_amdgcn_cvt_pk_f32_fp8((int)zw.x, true);  zv[2]=p.x;  zv[3]=p.y;
  p = z_pair((unsigned short)(zw.y & 0xffffu));      zv[4]=p.x;  zv[5]=p.y;
  p = __builtin_amdgcn_cvt_pk_f32_fp8((int)zw.y, true);  zv[6]=p.x;  zv[7]=p.y;
  p = z_pair((unsigned short)(zw.z & 0xffffu));      zv[8]=p.x;  zv[9]=p.y;
  p = __builtin_amdgcn_cvt_pk_f32_fp8((int)zw.z, true);  zv[10]=p.x; zv[11]=p.y;
  p = z_pair((unsigned short)(zw.w & 0xffffu));      zv[12]=p.x; zv[13]=p.y;
  p = __builtin_amdgcn_cvt_pk_f32_fp8((int)zw.w, true);  zv[14]=p.x; zv[15]=p.y;
#else
  short8v z0 = *(const short8v*)(zp);
  short8v z1 = *(const short8v*)(zp + 16);
  #pragma unroll
  for (int o = 0; o < 8; ++o){ zv[o] = bf2f((unsigned short)z0[o])*ZSCALE; zv[8+o] = bf2f((unsigned short)z1[o])*ZSCALE; }
#endif
  float sl = 0.f, sr = 0.f;
  #pragma unroll
  for (int o = 0; o < 16; ++o){
    sl += zv[o] * al[h*16+o]; sr += zv[o] * ar[h*16+o];
  }
  el[t] = f2bf(sl*(ZSCALE_INV*LOG2E)); er[t] = sr*(ZSCALE_INV*LOG2E);
}

// ---------------- per-node attention aggregate + residual + bias (+act) ----------------
// Head-parallel weights: lane = head*8 + edge-slot computes one (edge,head) weight;
// ds_swizzle broadcasts w within the 8-lane head group (LDS pipe, 0 VALU).
// CSR padded to x8 with dummy node (el=-inf -> w=0).
__global__ __launch_bounds__(256) void edge_agg(
    const unsigned char* __restrict__ Z, const unsigned short* __restrict__ el,
    const float* __restrict__ er, const int* __restrict__ offs,
    const int* __restrict__ pcnt, const int* __restrict__ csr,
    const unsigned short* __restrict__ Hin, const float* __restrict__ bias,
    unsigned short* __restrict__ Hout, int activate)
{
  int tid  = threadIdx.x;
  int lane = tid & 63;
  int n    = __builtin_amdgcn_readfirstlane((int)(blockIdx.x*4 + (tid >> 6)));
  if (n >= N_NODES) return;
  int head  = lane >> 3;
  int eslot = lane & 7;

  int lo = offs[n], pc = pcnt[n];
  float ern = er[(unsigned)n*8u + head];
  float acc0 = 0.f, acc1 = 0.f, sacc_p = 0.f;
  const unsigned lidx = (unsigned)(lane*2);          // dim index (2 dims/lane)

  for (int base = lo; base < lo + pc; base += 8){
    // vector csr load: lane's edge slot (replicated across head groups)
    unsigned sv = (unsigned)csr[base + eslot];
    // scalar csr for Z addressing (SALU/SMEM side)
    unsigned short zz[8];
    #pragma unroll
    for (int e = 0; e < 8; ++e){
      int se = csr[base + e];
      zz[e] = *(const unsigned short*)(Z + ((unsigned)se*128u + lidx)*ZB);
    }
    // one weight per lane: head x edge-slot
    float x = bf2f(el[sv*8u + head]) + ern;
    x = fmaxf(x, 0.2f*x);                            // leaky (commutes with log2e scale)
    float w = exp2f(x);                              // v_exp_f32
    sacc_p += w;
    int wi = __builtin_bit_cast(int, w);
    // broadcast slot e's weight within each 8-lane head group (literal swizzle imm)
#define SWZ_STEP(E) { \
      float we = __builtin_bit_cast(float, \
          __builtin_amdgcn_ds_swizzle(wi, 0x18 | ((E)<<5))); \
      f32x2 z = z_pair(zz[E]); \
      acc0 += we*z.x; \
      acc1 += we*z.y; }
    SWZ_STEP(0) SWZ_STEP(1) SWZ_STEP(2) SWZ_STEP(3)
    SWZ_STEP(4) SWZ_STEP(5) SWZ_STEP(6) SWZ_STEP(7)
#undef SWZ_STEP
  }
  // sum the 8 per-slot partials within each head group
  float sacc = sacc_p;
  sacc += __shfl_xor(sacc, 1, 64);
  sacc += __shfl_xor(sacc, 2, 64);
  sacc += __shfl_xor(sacc, 4, 64);
  float inv = (pc > 0) ? (ZSCALE_INV / sacc) : 0.f;  // fold fp8 x16 scale out
  unsigned hv = *(const unsigned*)(Hin + (unsigned)n*128u + lidx);
  int d = lane*2;
  float r0 = acc0*inv + lo16f(hv) + bias[d];
  float r1 = acc1*inv + hi16f(hv) + bias[d+1];
  if (activate){
    r0 = (r0 > 0.f) ? r0 : 0.01f*r0;
    r1 = (r1 > 0.f) ? r1 : 0.01f*r1;
  }
  unsigned outv = ((unsigned)f2bf(r1) << 16) | (unsigned)f2bf(r0);
  *(unsigned*)(Hout + (unsigned)n*128u + lidx) = outv;
}

// ---------------- L2 normalize + gather out = v[x] ----------------
__global__ __launch_bounds__(256) void norm_gather(const unsigned short* __restrict__ H,
    const int* __restrict__ x, float* __restrict__ out)
{
  int row = blockIdx.x*4 + (threadIdx.x >> 6);
  if (row >= BT) return;
  int lane = threadIdx.x & 63;
  unsigned xi = (unsigned)x[row];
  unsigned hv = *(const unsigned*)(H + xi*128u + (unsigned)(lane*2));
  float v0 = lo16f(hv), v1 = hi16f(hv);
  float ss = v0*v0 + v1*v1;
  #pragma unroll
  for (int m = 32; m; m >>= 1) ss += __shfl_xor(ss, m, 64);
  float sc = 1.f / fmaxf(sqrtf(ss), 1e-5f);
  int d = lane*2;
  out[(size_t)row*128 + d]     = v0*sc;
  out[(size_t)row*128 + d + 1] = v1*sc;
}

extern "C" void kernel_launch(void* const* d_in, const int* in_sizes, int n_in,
                              void* d_out, int out_size, void* d_ws, size_t ws_size,
                              hipStream_t stream)
{
  const float* emb = (const float*)d_in[0];
  const float* W0  = (const float*)d_in[1];
  const float* al0 = (const float*)d_in[2];
  const float* ar0 = (const float*)d_in[3];
  const float* b0  = (const float*)d_in[4];
  const float* W1  = (const float*)d_in[5];
  const float* al1 = (const float*)d_in[6];
  const float* ar1 = (const float*)d_in[7];
  const float* b1  = (const float*)d_in[8];
  const int* n_feat = (const int*)d_in[9];
  const int* srcv = (const int*)d_in[10];
  const int* dstv = (const int*)d_in[11];
  const int* xv   = (const int*)d_in[12];
  float* out = (float*)d_out;

  const int CSR_PAD = N_EDGES + NBKT*1792;               // padded csr capacity

  char* p = (char*)d_ws;
  auto alloc = [&](size_t b)->char*{ char* q = p; p += (b + 255) & ~(size_t)255; return q; };
  unsigned char*  Z   = (unsigned char*)alloc((size_t)(N_NODES+1)*128*ZB);  // +1 dummy row
  unsigned short* H1b = (unsigned short*)alloc((size_t)N_NODES*128*2);  // layer0 out, layer1 in/out
  unsigned short* Hb0 = (unsigned short*)alloc((size_t)N_NODES*128*2);  // bf16 gathered emb rows
  int* offs  = (int*)alloc((size_t)N_NODES*4);
  int* pcnt  = (int*)alloc((size_t)N_NODES*4);
  int* csr   = (int*)alloc((size_t)CSR_PAD*4);
  unsigned* ebuf = (unsigned*)alloc((size_t)N_EDGES*4);  // dead after p2fine; reused for el/er
  int* bh    = (int*)alloc((size_t)NBKT*NCHUNK*4);
  int* bsum  = (int*)alloc(256*4);
  unsigned short* Wt0 = (unsigned short*)alloc(128*128*2);
  unsigned short* Wt1 = (unsigned short*)alloc(128*128*2);
  unsigned short* el = (unsigned short*)ebuf;            // (N+1)*8 bf16
  float* er = (float*)(((char*)ebuf) + (((size_t)(N_NODES+1)*8*2 + 255) & ~(size_t)255)); // (N+1)*8 f32

  const int NSCAN = NBKT*NCHUNK;                         // 57344

  // CSR build (no global atomics)
  p1hist<<<NCHUNK, 256, 0, stream>>>(dstv, bh);
  scan_partial<<<NSCAN/256, 256, 0, stream>>>(bh, bh, bsum, NSCAN);
  scan_add2<<<NSCAN/256, 256, 0, stream>>>(bh, bsum, NSCAN/256, NSCAN);
  p1scat<<<NCHUNK, 256, 0, stream>>>(srcv, dstv, bh, ebuf);
  p2fine<<<NBKT, 256, 0, stream>>>(ebuf, bh, offs, pcnt, csr);

  twt_kernel<<<128, 256, 0, stream>>>(W0, W1, Wt0, Wt1);

  int gemm_grid = (N_NODES + 127)/128;
  int agg_grid  = (N_NODES + 3)/4;
  int eler_grid = ((N_NODES+1)*8 + 255)/256;

  // layer 0 (rows gathered emb[n_feat] -> also Hb0; activation on)
  gemm_nt<0><<<gemm_grid, 256, 0, stream>>>(emb, n_feat, Wt0, Z, Hb0);
  eler_kernel<<<eler_grid, 256, 0, stream>>>(Z, al0, ar0, el, er);
  edge_agg<<<agg_grid, 256, 0, stream>>>(Z, el, er, offs, pcnt, csr, Hb0, b0, H1b, 1);
  // layer 1 (bf16 input; in-place residual safe: wave reads row n before writing it)
  gemm_nt<1><<<gemm_grid, 256, 0, stream>>>(H1b, nullptr, Wt1, Z, nullptr);
  eler_kernel<<<eler_grid, 256, 0, stream>>>(Z, al1, ar1, el, er);
  edge_agg<<<agg_grid, 256, 0, stream>>>(Z, el, er, offs, pcnt, csr, H1b, b1, H1b, 0);
  // normalize + output gather
  norm_gather<<<(BT + 3)/4, 256, 0, stream>>>(H1b, xv, out);
}